// Round 21
// baseline (130.046 us; speedup 1.0000x reference)
//
#include <hip/hip_runtime.h>

typedef short bf16x8 __attribute__((ext_vector_type(8)));
typedef float f32x4 __attribute__((ext_vector_type(4)));

#define L_SEQ 2048

__device__ inline unsigned short f2bf(float f) {
    unsigned int u = __builtin_bit_cast(unsigned int, f);
    u += 0x7FFFu + ((u >> 16) & 1u);
    return (unsigned short)(u >> 16);
}

__device__ inline float exp2_fast(float x) {
    float r;
    asm volatile("v_exp_f32 %0, %1" : "=v"(r) : "v"(x));
    return r;
}

// async global->LDS DMA, 16B per lane; LDS dest must be wave-uniform base + lane*16.
__device__ inline void gload16(const void* g, void* l) {
    __builtin_amdgcn_global_load_lds((const __attribute__((address_space(1))) void*)g,
                                     (__attribute__((address_space(3))) void*)l, 16, 0, 0);
}

// ---------------------------------------------------------------- M_h = Pq_h @ Pk_h^T  [16][64][64]
__global__ __launch_bounds__(256) void compute_M(const float* __restrict__ Pq,
                                                 const float* __restrict__ Pk,
                                                 float* __restrict__ M) {
    const int h = blockIdx.x, dg = blockIdx.y, t = threadIdx.x;
    const int e = t & 63, dr = t >> 6;
    __shared__ float Pql[4][512];
    for (int i = t; i < 512; i += 256) {
#pragma unroll
        for (int rr = 0; rr < 4; ++rr)
            Pql[rr][i] = Pq[((size_t)h * 64 + dg * 4 + rr) * 512 + i];
    }
    __syncthreads();
    const float4* a = (const float4*)Pql[dr];
    const float4* b = (const float4*)(Pk + ((size_t)h * 64 + e) * 512);
    float s = 0.f;
#pragma unroll 4
    for (int r = 0; r < 128; ++r) {
        float4 x = a[r], y = b[r];
        s = fmaf(x.x, y.x, fmaf(x.y, y.y, fmaf(x.z, y.z, fmaf(x.w, y.w, s))));
    }
    M[((size_t)h * 64 + dg * 4 + dr) * 64 + e] =
        s * (0.044194173824159216f * 1.4426950408889634f); // 1/sqrt(512) * log2(e)
}

// ---------------------------------------------------------------- fbias[h][d] = log2e * sum_k coef[h][k]*s_k*cos(pi*(d+.5)*k/L)
__global__ void bias_table_kernel(const float* __restrict__ coef, float* __restrict__ fbias) {
    int i = blockIdx.x * 256 + threadIdx.x;
    if (i >= 16 * 2048) return;
    int h = i >> 11, d = i & 2047;
    const float pi = 3.14159265358979323846f;
    float acc = 0.f;
#pragma unroll
    for (int k = 0; k < 6; ++k) {
        float sc = (k == 0) ? 0.022097086912079608f : 0.03125f; // sqrt(1/2048), sqrt(2/2048)
        float arg = pi * ((float)d + 0.5f) * (float)k * (1.0f / 2048.0f);
        acc += coef[h * 6 + k] * sc * cosf(arg);
    }
    fbias[i] = acc * 1.4426950408889634f; // log2(e)
}

// ---------------------------------------------------------------- Wt q-region via per-head GEMM
__global__ __launch_bounds__(256) void build_wtq(
    const float* __restrict__ Wq, const float* __restrict__ bq, const float* __restrict__ M,
    unsigned short* __restrict__ Wt, float* __restrict__ biasp) {
    const int hh = blockIdx.x, kt = blockIdx.y, t = threadIdx.x;
    const int k0 = kt * 64;
    __shared__ float Wql[64 * 68];  // rows stride 68 (16B-aligned, conflict-light)
    __shared__ float MlT[64 * 65];  // MlT[e][d], stride 65 (odd -> conflict-free)

    for (int i = t; i < 4096; i += 256) {
        int d = i >> 6, e = i & 63;
        MlT[e * 65 + d] = M[(size_t)hh * 4096 + i];
    }
#pragma unroll
    for (int i = 0; i < 4; ++i) {
        int cc = i * 256 + t;                 // 1024 float4 chunks
        int row = cc >> 4, c4 = cc & 15;
        *(float4*)&Wql[row * 68 + c4 * 4] =
            *(const float4*)(Wq + (size_t)(k0 + row) * 1024 + hh * 64 + c4 * 4);
    }
    __syncthreads();

    const int e = t >> 2, kq = t & 3;
    float me[64];
#pragma unroll
    for (int d = 0; d < 64; ++d) me[d] = MlT[e * 65 + d];

    float acc[16];
#pragma unroll
    for (int i = 0; i < 16; ++i) acc[i] = 0.f;
#pragma unroll
    for (int kk = 0; kk < 16; ++kk) {
        int row = kq * 16 + kk;
#pragma unroll
        for (int d4 = 0; d4 < 16; ++d4) {
            float4 w = *(const float4*)&Wql[row * 68 + d4 * 4];
            acc[kk] = fmaf(w.x, me[d4 * 4 + 0],
                      fmaf(w.y, me[d4 * 4 + 1],
                      fmaf(w.z, me[d4 * 4 + 2],
                      fmaf(w.w, me[d4 * 4 + 3], acc[kk]))));
        }
    }
    unsigned short* dp = Wt + (size_t)(hh * 64 + e) * 1024 + k0 + kq * 16;
#pragma unroll
    for (int q8 = 0; q8 < 2; ++q8) {
        unsigned short o8[8];
#pragma unroll
        for (int j = 0; j < 8; ++j) o8[j] = f2bf(acc[q8 * 8 + j]);
        *(uint4*)(dp + q8 * 8) = *(const uint4*)o8;
    }
    if (kt == 0 && t < 64) {
        float s = 0.f;
#pragma unroll
        for (int d = 0; d < 64; ++d) s = fmaf(bq[hh * 64 + d], MlT[t * 65 + d], s);
        biasp[hh * 64 + t] = s;
    }
}

// ---------------------------------------------------------------- Wt k/v-region: tiled transpose
__global__ __launch_bounds__(256) void transpose_wkv(
    const float* __restrict__ Wk, const float* __restrict__ Wv,
    const float* __restrict__ bk, const float* __restrict__ bv,
    unsigned short* __restrict__ Wt, float* __restrict__ biasp) {
    const int ct = blockIdx.x, kt2 = blockIdx.y, sel = blockIdx.z;
    const float* W = sel ? Wv : Wk;
    __shared__ float tl[64 * 68];
    const int t = threadIdx.x;
    const int k0 = kt2 * 64, c0 = ct * 64;
#pragma unroll
    for (int i = 0; i < 4; ++i) {
        int cc = i * 256 + t;
        int r = cc >> 4, c4 = cc & 15;
        *(float4*)&tl[r * 68 + c4 * 4] =
            *(const float4*)(W + (size_t)(k0 + r) * 1024 + c0 + c4 * 4);
    }
    __syncthreads();
    const int c = t >> 2, seg = t & 3; // 64 cols x 4 segments of 16 k
    unsigned short* dp = Wt + (size_t)(1024 + sel * 1024 + c0 + c) * 1024 + k0 + seg * 16;
#pragma unroll
    for (int q8 = 0; q8 < 2; ++q8) {
        unsigned short o8[8];
#pragma unroll
        for (int j = 0; j < 8; ++j) o8[j] = f2bf(tl[(seg * 16 + q8 * 8 + j) * 68 + c]);
        *(uint4*)(dp + q8 * 8) = *(const uint4*)o8;
    }
    if (kt2 == 0 && t < 64) biasp[1024 + sel * 1024 + c0 + t] = (sel ? bv : bk)[c0 + t];
}

// ---------------------------------------------------------------- X = bf16(hidden_states) [4096][1024]
__global__ __launch_bounds__(256) void cast_hs_kernel(const float* __restrict__ hs,
                                                      unsigned short* __restrict__ X) {
    const int i = (blockIdx.x * 256 + threadIdx.x) * 4;
    float4 v = *(const float4*)(hs + i);
    unsigned short o[4] = {f2bf(v.x), f2bf(v.y), f2bf(v.z), f2bf(v.w)};
    *(uint2*)(X + i) = *(const uint2*)o;
}

// ---------------------------------------------------------------- C[4096][3072] = X @ Wt^T + biasp -> q~,k bf16 [BH][L][64]; v written TRANSPOSED to vt [BH][64][L]
// 8 waves (2M x 4N), 128x128 tile, BK=64. Counted-vmcnt pipeline (T4).
__global__ __launch_bounds__(512) void gemm_qkv(
    const unsigned short* __restrict__ X, const unsigned short* __restrict__ Wt,
    const float* __restrict__ biasp,
    unsigned short* __restrict__ qs, unsigned short* __restrict__ ksd,
    unsigned short* __restrict__ vt) {
    __shared__ __align__(16) unsigned short shm[4 * 8192]; // 64 KB: A dbuf | B dbuf; reused as epilogue scratch

    const int bn = blockIdx.x, bm = blockIdx.y;
    const int m0 = bm * 128, n0 = bn * 128;
    const int t = threadIdx.x, wave = t >> 6, lane = t & 63, g = lane >> 4, li = lane & 15;
    const int wr = wave >> 2, wc = wave & 3;

    const int rowb = t >> 3;
    const int soff = ((t & 7) ^ (rowb & 7)) * 8; // row+64 has same row&7
    const unsigned short* Xrow = X + (size_t)(m0 + rowb) * 1024 + soff;
    const unsigned short* Wrow = Wt + (size_t)(n0 + rowb) * 1024 + soff;

    f32x4 acc[4][2];
#pragma unroll
    for (int i = 0; i < 4; ++i)
#pragma unroll
        for (int j = 0; j < 2; ++j) acc[i][j] = (f32x4){0.f, 0.f, 0.f, 0.f};

    // prologue: stage kt=0 into buffer 0 (4 loads/thread)
#pragma unroll
    for (int i = 0; i < 2; ++i) {
        gload16(Xrow + (size_t)i * 64 * 1024, &shm[(i * 512 + t) * 8]);
        gload16(Wrow + (size_t)i * 64 * 1024, &shm[16384 + (i * 512 + t) * 8]);
    }

    for (int kt = 0; kt < 16; ++kt) {
        const int cur = kt & 1;
        __builtin_amdgcn_s_barrier(); // all waves done reading buf[cur^1] (prev compute)
        if (kt < 15) {
            const int k0n = (kt + 1) * 64;
            unsigned short* An = &shm[(cur ^ 1) * 8192];
            unsigned short* Bn = &shm[16384 + (cur ^ 1) * 8192];
#pragma unroll
            for (int i = 0; i < 2; ++i) {
                gload16(Xrow + (size_t)i * 64 * 1024 + k0n, &An[(i * 512 + t) * 8]);
                gload16(Wrow + (size_t)i * 64 * 1024 + k0n, &Bn[(i * 512 + t) * 8]);
            }
            asm volatile("s_waitcnt vmcnt(4)" ::: "memory"); // cur's 4 landed; next's in flight
        } else {
            asm volatile("s_waitcnt vmcnt(0)" ::: "memory");
        }
        __builtin_amdgcn_s_barrier(); // every wave's cur-loads landed
        const unsigned short* Al = &shm[cur * 8192];
        const unsigned short* Bl = &shm[16384 + cur * 8192];
        __builtin_amdgcn_s_setprio(1);
#pragma unroll
        for (int ks = 0; ks < 2; ++ks) {
            bf16x8 af[4], bf[2];
#pragma unroll
            for (int mi = 0; mi < 4; ++mi) {
                int row = wr * 64 + mi * 16 + li;
                af[mi] = *(const bf16x8*)&Al[row * 64 + ((ks * 4 + g) ^ (row & 7)) * 8];
            }
#pragma unroll
            for (int ni = 0; ni < 2; ++ni) {
                int row = wc * 32 + ni * 16 + li;
                bf[ni] = *(const bf16x8*)&Bl[row * 64 + ((ks * 4 + g) ^ (row & 7)) * 8];
            }
#pragma unroll
            for (int mi = 0; mi < 4; ++mi)
#pragma unroll
                for (int ni = 0; ni < 2; ++ni)
                    acc[mi][ni] = __builtin_amdgcn_mfma_f32_16x16x32_bf16(af[mi], bf[ni],
                                                                          acc[mi][ni], 0, 0, 0);
        }
        __builtin_amdgcn_s_setprio(0);
    }
    __syncthreads(); // all compute done before scratch reuse of shm

    float bvals[2];
#pragma unroll
    for (int ni = 0; ni < 2; ++ni) bvals[ni] = biasp[n0 + wc * 32 + ni * 16 + li];

    const int region = n0 >> 10; // block-uniform: 0=q, 1=k, 2=v
    float* scr = (float*)shm;

    if (region < 2) {
        // q/k: per-wave scratch 16 rows x 36 stride
        float* wf = scr + wave * (16 * 36);
        unsigned short* dstbase = region == 0 ? qs : ksd;
        const int ncol0 = n0 + wc * 32;
        const int hh = (ncol0 & 1023) >> 6;
        const int dcol = (ncol0 & 63) + (lane & 3) * 8;
        const int lr = lane >> 2;
#pragma unroll
        for (int mi = 0; mi < 4; ++mi) {
#pragma unroll
            for (int r = 0; r < 4; ++r) {
                int rowl = g * 4 + r;
#pragma unroll
                for (int ni = 0; ni < 2; ++ni)
                    wf[rowl * 36 + ni * 16 + li] = acc[mi][ni][r] + bvals[ni];
            }
            int m = m0 + wr * 64 + mi * 16 + lr;
            int bb = m >> 11, l = m & 2047;
            unsigned short* dp = dstbase + ((size_t)(bb * 16 + hh) * 2048 + l) * 64 + dcol;
            float4 a0 = *(const float4*)&wf[lr * 36 + (lane & 3) * 8];
            float4 a1 = *(const float4*)&wf[lr * 36 + (lane & 3) * 8 + 4];
            unsigned short o8[8] = {f2bf(a0.x), f2bf(a0.y), f2bf(a0.z), f2bf(a0.w),
                                    f2bf(a1.x), f2bf(a1.y), f2bf(a1.z), f2bf(a1.w)};
            *(uint4*)dp = *(const uint4*)o8;
        }
    } else {
        // v: per-wave scratch 32 rows x 36 stride
        float* wf = scr + wave * (32 * 36);
        const int d32 = lane & 31, half = lane >> 5;
        const int dglob = ((n0 + wc * 32) & 63) + d32;
        const int hh = ((n0 + wc * 32) & 1023) >> 6;
#pragma unroll
        for (int ch2 = 0; ch2 < 2; ++ch2) {
#pragma unroll
            for (int mi2 = 0; mi2 < 2; ++mi2) {
                int mi = ch2 * 2 + mi2;
#pragma unroll
                for (int r = 0; r < 4; ++r) {
                    int rowl = mi2 * 16 + g * 4 + r;
#pragma unroll
                    for (int ni = 0; ni < 2; ++ni)
                        wf[rowl * 36 + ni * 16 + li] = acc[mi][ni][r] + bvals[ni];
                }
            }
            int l0 = m0 + wr * 64 + ch2 * 32;
            int bb = l0 >> 11, lb = (l0 & 2047) + half * 16;
            unsigned short* dp = vt + ((size_t)(bb * 16 + hh) * 64 + dglob) * 2048 + lb;
#pragma unroll
            for (int q8 = 0; q8 < 2; ++q8) {
                unsigned short o8[8];
#pragma unroll
                for (int j = 0; j < 8; ++j)
                    o8[j] = f2bf(wf[(half * 16 + q8 * 8 + j) * 36 + d32]);
                *(uint4*)(dp + q8 * 8) = *(const uint4*)o8;
            }
        }
    }
}

// ---------------------------------------------------------------- flash attention (swapped-QK^T)
// grid (16 qtiles, 32 bh), 512 threads = 8 waves x 16 q-rows. KVBLK=128, double-
// buffered, DMA-staged, counted-vmcnt pipeline. Swapped operands: S^T = mfma(K,Q)
// puts one q-row per thread (q = im+li, 16 j-values). P^T stored per-wave as
// [q][j] with chunk swizzle (c ^= (li&7)<<1, bit0 kept -> b128 reads stay in
// j-order): 4 x ds_write_b64 + 2 x ds_read_b128. PV: O^T = mfma(V^T, P^T) -- V
// fragments are the same reads as before (Vlds is [d][j]). Denominator = per-
// thread sum of bf16-rounded P + shfl_xor(16,32). No online max (scores O(1)).
__global__ __launch_bounds__(512) void attn_kernel(
    const unsigned short* __restrict__ qs, const unsigned short* __restrict__ ksrc,
    const unsigned short* __restrict__ vt, const float* __restrict__ fbias,
    float* __restrict__ out) {
    const int qt = blockIdx.x, bh = blockIdx.y;
    const int h = bh & 15, b = bh >> 4;
    const int t = threadIdx.x, wave = t >> 6, lane = t & 63, g = lane >> 4, li = lane & 15;

    __shared__ unsigned short Klds[2][2][64 * 64];
    __shared__ unsigned short Vlds[2][2][64 * 64];
    __shared__ unsigned short Plds[8][16 * 64]; // per-wave P^T: [q=li][j], chunk-swizzled

    const float* fbh = fbias + (size_t)h * 2048;
    const unsigned short* Kg = ksrc + (size_t)bh * L_SEQ * 64;
    const unsigned short* Vg = vt + (size_t)bh * 64 * L_SEQ;

    const int im = qt * 128 + wave * 16;
    const unsigned short* qb = qs + ((size_t)bh * L_SEQ + im + li) * 64;
    bf16x8 qa0 = *(const bf16x8*)(qb + g * 8);        // d = g*8..+7   (B-frag ks=0)
    bf16x8 qa1 = *(const bf16x8*)(qb + 32 + g * 8);   // d = 32+g*8..  (B-frag ks=1)

    f32x4 o[4]; // O^T: thread holds d = db*16 + g*4 + r, q = im+li
#pragma unroll
    for (int i = 0; i < 4; ++i) o[i] = (f32x4){0.f, 0.f, 0.f, 0.f};
    float denacc = 0.f;

    const int iout = im + li; // this thread's q-row
    int lo = iout - 32; lo = lo < 0 ? 0 : (lo > 1984 ? 1984 : lo);

    // wave-level band union: q-rows [im, im+15]
    int lo_min = im - 32; lo_min = lo_min < 0 ? 0 : (lo_min > 1984 ? 1984 : lo_min);
    int hi_tmp = im + 15 - 32; hi_tmp = hi_tmp < 0 ? 0 : (hi_tmp > 1984 ? 1984 : hi_tmp);
    const int hi_max = hi_tmp + 63;

    const int swz = (li & 7) << 1; // P^T chunk swizzle (bits 1..3 only)

    // per-thread DMA chunk geometry (16B per tensor per sub-tile per thread)
    const int r0 = t >> 3, s0 = ((t & 7) ^ (r0 & 7)) * 8;

    // prologue: stage tile-pair 0 into buffer 0 (4 loads/thread)
#pragma unroll
    for (int sub = 0; sub < 2; ++sub) {
        gload16(Kg + (size_t)(sub * 64 + r0) * 64 + s0, &Klds[0][sub][t * 8]);
        gload16(Vg + (size_t)r0 * L_SEQ + sub * 64 + s0, &Vlds[0][sub][t * 8]);
    }

    for (int jp = 0; jp < 16; ++jp) {
        const int cur = jp & 1;

        __builtin_amdgcn_s_barrier(); // all waves done reading buf[cur^1]
        if (jp < 15) {
            const int jb = (jp + 1) * 128;
#pragma unroll
            for (int sub = 0; sub < 2; ++sub) {
                gload16(Kg + (size_t)(jb + sub * 64 + r0) * 64 + s0, &Klds[cur ^ 1][sub][t * 8]);
                gload16(Vg + (size_t)r0 * L_SEQ + jb + sub * 64 + s0, &Vlds[cur ^ 1][sub][t * 8]);
            }
            asm volatile("s_waitcnt vmcnt(4)" ::: "memory"); // cur's 4 landed
        } else {
            asm volatile("s_waitcnt vmcnt(0)" ::: "memory");
        }
        __builtin_amdgcn_s_barrier(); // every wave's cur-loads landed

#pragma unroll
        for (int sub = 0; sub < 2; ++sub) {
            const int j0 = jp * 128 + sub * 64;
            const unsigned short* Kl = Klds[cur][sub];
            const unsigned short* Vl = Vlds[cur][sub];

            // S^T[j][q] = mfma(A=K-frag, B=Q-frag): same reads, swapped operands.
            // C: row = j = nb*16 + g*4 + r, col = q = li.
            f32x4 s[4];
#pragma unroll
            for (int nb = 0; nb < 4; ++nb) s[nb] = (f32x4){0.f, 0.f, 0.f, 0.f};
            __builtin_amdgcn_s_setprio(1);
#pragma unroll
            for (int ks = 0; ks < 2; ++ks) {
                bf16x8 qf = ks ? qa1 : qa0;
#pragma unroll
                for (int nb = 0; nb < 4; ++nb) {
                    int row = nb * 16 + li;
                    bf16x8 kf = *(const bf16x8*)&Kl[row * 64 + ((ks * 4 + g) ^ (row & 7)) * 8];
                    s[nb] = __builtin_amdgcn_mfma_f32_16x16x32_bf16(kf, qf, s[nb], 0, 0, 0);
                }
            }
            __builtin_amdgcn_s_setprio(0);

            // softmax: one q-row per thread; write P^T chunks (4 x b64), sum bf16-P
            const bool bias_tile = (j0 + 63 >= lo_min) && (j0 <= hi_max);
            unsigned short* Pw = Plds[wave];
            float den = 0.f;
#pragma unroll
            for (int nb = 0; nb < 4; ++nb) {
                unsigned int uu[4];
#pragma unroll
                for (int r = 0; r < 4; ++r) {
                    int j = j0 + nb * 16 + g * 4 + r;
                    float x = s[nb][r];
                    if (bias_tile) {
                        int dd = iout - j; dd = dd < 0 ? -dd : dd;
                        if ((unsigned)(j - lo) < 64u) x += fbh[dd];
                    }
                    unsigned int u = (unsigned int)f2bf(exp2_fast(x));
                    den += __builtin_bit_cast(float, u << 16);
                    uu[r] = u;
                }
                int cs = (nb * 4 + g) ^ swz;
                uint2 pw2;
                pw2.x = uu[0] | (uu[1] << 16);
                pw2.y = uu[2] | (uu[3] << 16);
                *(uint2*)&Pw[li * 64 + cs * 4] = pw2;
            }
            den += __shfl_xor(den, 16);
            den += __shfl_xor(den, 32);
            denacc += den;

            // P^T B-fragments: lane needs j = ks*32 + g*8 .. +7 of its q-row
            bf16x8 pb0 = *(const bf16x8*)&Pw[li * 64 + ((g * 2) ^ swz) * 4];
            bf16x8 pb1 = *(const bf16x8*)&Pw[li * 64 + ((8 + g * 2) ^ swz) * 4];

            // PV: O^T[d][q] = mfma(A=V^T-frag, B=P^T-frag); V reads unchanged.
            __builtin_amdgcn_s_setprio(1);
#pragma unroll
            for (int db = 0; db < 4; ++db) {
                int row = db * 16 + li;
                bf16x8 v0 = *(const bf16x8*)&Vl[row * 64 + ((0 + g) ^ (row & 7)) * 8];
                bf16x8 v1 = *(const bf16x8*)&Vl[row * 64 + ((4 + g) ^ (row & 7)) * 8];
                o[db] = __builtin_amdgcn_mfma_f32_16x16x32_bf16(v0, pb0, o[db], 0, 0, 0);
                o[db] = __builtin_amdgcn_mfma_f32_16x16x32_bf16(v1, pb1, o[db], 0, 0, 0);
            }
            __builtin_amdgcn_s_setprio(0);
        }
    }

    // epilogue: thread owns q=iout, d = db*16 + g*4 + (0..3) -> 4 x 16B stores
    float rl = 1.f / denacc;
    float* ob2 = out + ((size_t)b * L_SEQ + iout) * 1024 + h * 64;
#pragma unroll
    for (int db = 0; db < 4; ++db) {
        f32x4 vsc = o[db];
        vsc[0] *= rl; vsc[1] *= rl; vsc[2] *= rl; vsc[3] *= rl;
        *(f32x4*)(ob2 + db * 16 + g * 4) = vsc;
    }
}

// ----------------------------------------------------------------
extern "C" void kernel_launch(void* const* d_in, const int* in_sizes, int n_in,
                              void* d_out, int out_size, void* d_ws, size_t ws_size,
                              hipStream_t stream) {
    const float* hs = (const float*)d_in[0];
    const float* Wq = (const float*)d_in[1];
    const float* bq = (const float*)d_in[2];
    const float* Wk = (const float*)d_in[3];
    const float* bk = (const float*)d_in[4];
    const float* Wv = (const float*)d_in[5];
    const float* bv = (const float*)d_in[6];
    const float* coef = (const float*)d_in[7];
    const float* Pq = (const float*)d_in[8];
    const float* Pk = (const float*)d_in[9];
    float* out = (float*)d_out;

    char* w = (char*)d_ws;
    float* M = (float*)(w);                              // 256 KB
    float* fbias = (float*)(w + 0x40000);                // 128 KB
    float* biasp = (float*)(w + 0x60000);                // 12 KB
    unsigned short* Wt = (unsigned short*)(w + 0x70000); // 6 MB
    unsigned short* X = (unsigned short*)(w + 0x670000); // 8 MB
    unsigned short* qs = (unsigned short*)(w + 0xE70000);
    unsigned short* ks = (unsigned short*)(w + 0x1670000);
    unsigned short* vt = (unsigned short*)(w + 0x2670000);

    hipLaunchKernelGGL(compute_M, dim3(16, 16), dim3(256), 0, stream, Pq, Pk, M);
    hipLaunchKernelGGL(bias_table_kernel, dim3(128), dim3(256), 0, stream, coef, fbias);
    hipLaunchKernelGGL(build_wtq, dim3(16, 16), dim3(256), 0, stream, Wq, bq, M, Wt, biasp);
    hipLaunchKernelGGL(transpose_wkv, dim3(16, 16, 2), dim3(256), 0, stream,
                       Wk, Wv, bk, bv, Wt, biasp);
    hipLaunchKernelGGL(cast_hs_kernel, dim3(4096), dim3(256), 0, stream, hs, X);
    hipLaunchKernelGGL(gemm_qkv, dim3(24, 32), dim3(512), 0, stream, X, Wt, biasp, qs, ks, vt);
    hipLaunchKernelGGL(attn_kernel, dim3(16, 32), dim3(512), 0, stream, qs, ks, vt, fbias, out);
}

// Round 22
// 124.159 us; speedup vs baseline: 1.0474x; 1.0474x over previous
//
#include <hip/hip_runtime.h>

typedef short bf16x8 __attribute__((ext_vector_type(8)));
typedef float f32x4 __attribute__((ext_vector_type(4)));

#define L_SEQ 2048

__device__ inline unsigned short f2bf(float f) {
    unsigned int u = __builtin_bit_cast(unsigned int, f);
    u += 0x7FFFu + ((u >> 16) & 1u);
    return (unsigned short)(u >> 16);
}

__device__ inline float exp2_fast(float x) {
    float r;
    asm volatile("v_exp_f32 %0, %1" : "=v"(r) : "v"(x));
    return r;
}

// async global->LDS DMA, 16B per lane; LDS dest must be wave-uniform base + lane*16.
__device__ inline void gload16(const void* g, void* l) {
    __builtin_amdgcn_global_load_lds((const __attribute__((address_space(1))) void*)g,
                                     (__attribute__((address_space(3))) void*)l, 16, 0, 0);
}

// ---------------------------------------------------------------- M_h = Pq_h @ Pk_h^T  [16][64][64]
__global__ __launch_bounds__(256) void compute_M(const float* __restrict__ Pq,
                                                 const float* __restrict__ Pk,
                                                 float* __restrict__ M) {
    const int h = blockIdx.x, dg = blockIdx.y, t = threadIdx.x;
    const int e = t & 63, dr = t >> 6;
    __shared__ float Pql[4][512];
    for (int i = t; i < 512; i += 256) {
#pragma unroll
        for (int rr = 0; rr < 4; ++rr)
            Pql[rr][i] = Pq[((size_t)h * 64 + dg * 4 + rr) * 512 + i];
    }
    __syncthreads();
    const float4* a = (const float4*)Pql[dr];
    const float4* b = (const float4*)(Pk + ((size_t)h * 64 + e) * 512);
    float s = 0.f;
#pragma unroll 4
    for (int r = 0; r < 128; ++r) {
        float4 x = a[r], y = b[r];
        s = fmaf(x.x, y.x, fmaf(x.y, y.y, fmaf(x.z, y.z, fmaf(x.w, y.w, s))));
    }
    M[((size_t)h * 64 + dg * 4 + dr) * 64 + e] =
        s * (0.044194173824159216f * 1.4426950408889634f); // 1/sqrt(512) * log2(e)
}

// ---------------------------------------------------------------- fbias[h][d] = log2e * sum_k coef[h][k]*s_k*cos(pi*(d+.5)*k/L)
__global__ void bias_table_kernel(const float* __restrict__ coef, float* __restrict__ fbias) {
    int i = blockIdx.x * 256 + threadIdx.x;
    if (i >= 16 * 2048) return;
    int h = i >> 11, d = i & 2047;
    const float pi = 3.14159265358979323846f;
    float acc = 0.f;
#pragma unroll
    for (int k = 0; k < 6; ++k) {
        float sc = (k == 0) ? 0.022097086912079608f : 0.03125f; // sqrt(1/2048), sqrt(2/2048)
        float arg = pi * ((float)d + 0.5f) * (float)k * (1.0f / 2048.0f);
        acc += coef[h * 6 + k] * sc * cosf(arg);
    }
    fbias[i] = acc * 1.4426950408889634f; // log2(e)
}

// ---------------------------------------------------------------- Wt q-region via per-head GEMM
__global__ __launch_bounds__(256) void build_wtq(
    const float* __restrict__ Wq, const float* __restrict__ bq, const float* __restrict__ M,
    unsigned short* __restrict__ Wt, float* __restrict__ biasp) {
    const int hh = blockIdx.x, kt = blockIdx.y, t = threadIdx.x;
    const int k0 = kt * 64;
    __shared__ float Wql[64 * 68];  // rows stride 68 (16B-aligned, conflict-light)
    __shared__ float MlT[64 * 65];  // MlT[e][d], stride 65 (odd -> conflict-free)

    for (int i = t; i < 4096; i += 256) {
        int d = i >> 6, e = i & 63;
        MlT[e * 65 + d] = M[(size_t)hh * 4096 + i];
    }
#pragma unroll
    for (int i = 0; i < 4; ++i) {
        int cc = i * 256 + t;                 // 1024 float4 chunks
        int row = cc >> 4, c4 = cc & 15;
        *(float4*)&Wql[row * 68 + c4 * 4] =
            *(const float4*)(Wq + (size_t)(k0 + row) * 1024 + hh * 64 + c4 * 4);
    }
    __syncthreads();

    const int e = t >> 2, kq = t & 3;
    float me[64];
#pragma unroll
    for (int d = 0; d < 64; ++d) me[d] = MlT[e * 65 + d];

    float acc[16];
#pragma unroll
    for (int i = 0; i < 16; ++i) acc[i] = 0.f;
#pragma unroll
    for (int kk = 0; kk < 16; ++kk) {
        int row = kq * 16 + kk;
#pragma unroll
        for (int d4 = 0; d4 < 16; ++d4) {
            float4 w = *(const float4*)&Wql[row * 68 + d4 * 4];
            acc[kk] = fmaf(w.x, me[d4 * 4 + 0],
                      fmaf(w.y, me[d4 * 4 + 1],
                      fmaf(w.z, me[d4 * 4 + 2],
                      fmaf(w.w, me[d4 * 4 + 3], acc[kk]))));
        }
    }
    unsigned short* dp = Wt + (size_t)(hh * 64 + e) * 1024 + k0 + kq * 16;
#pragma unroll
    for (int q8 = 0; q8 < 2; ++q8) {
        unsigned short o8[8];
#pragma unroll
        for (int j = 0; j < 8; ++j) o8[j] = f2bf(acc[q8 * 8 + j]);
        *(uint4*)(dp + q8 * 8) = *(const uint4*)o8;
    }
    if (kt == 0 && t < 64) {
        float s = 0.f;
#pragma unroll
        for (int d = 0; d < 64; ++d) s = fmaf(bq[hh * 64 + d], MlT[t * 65 + d], s);
        biasp[hh * 64 + t] = s;
    }
}

// ---------------------------------------------------------------- Wt k/v-region: tiled transpose
__global__ __launch_bounds__(256) void transpose_wkv(
    const float* __restrict__ Wk, const float* __restrict__ Wv,
    const float* __restrict__ bk, const float* __restrict__ bv,
    unsigned short* __restrict__ Wt, float* __restrict__ biasp) {
    const int ct = blockIdx.x, kt2 = blockIdx.y, sel = blockIdx.z;
    const float* W = sel ? Wv : Wk;
    __shared__ float tl[64 * 68];
    const int t = threadIdx.x;
    const int k0 = kt2 * 64, c0 = ct * 64;
#pragma unroll
    for (int i = 0; i < 4; ++i) {
        int cc = i * 256 + t;
        int r = cc >> 4, c4 = cc & 15;
        *(float4*)&tl[r * 68 + c4 * 4] =
            *(const float4*)(W + (size_t)(k0 + r) * 1024 + c0 + c4 * 4);
    }
    __syncthreads();
    const int c = t >> 2, seg = t & 3; // 64 cols x 4 segments of 16 k
    unsigned short* dp = Wt + (size_t)(1024 + sel * 1024 + c0 + c) * 1024 + k0 + seg * 16;
#pragma unroll
    for (int q8 = 0; q8 < 2; ++q8) {
        unsigned short o8[8];
#pragma unroll
        for (int j = 0; j < 8; ++j) o8[j] = f2bf(tl[(seg * 16 + q8 * 8 + j) * 68 + c]);
        *(uint4*)(dp + q8 * 8) = *(const uint4*)o8;
    }
    if (kt2 == 0 && t < 64) biasp[1024 + sel * 1024 + c0 + t] = (sel ? bv : bk)[c0 + t];
}

// ---------------------------------------------------------------- X = bf16(hidden_states) [4096][1024]
__global__ __launch_bounds__(256) void cast_hs_kernel(const float* __restrict__ hs,
                                                      unsigned short* __restrict__ X) {
    const int i = (blockIdx.x * 256 + threadIdx.x) * 4;
    float4 v = *(const float4*)(hs + i);
    unsigned short o[4] = {f2bf(v.x), f2bf(v.y), f2bf(v.z), f2bf(v.w)};
    *(uint2*)(X + i) = *(const uint2*)o;
}

// ---------------------------------------------------------------- C[4096][3072] = X @ Wt^T + biasp -> q~,k bf16 [BH][L][64]; v written TRANSPOSED to vt [BH][64][L]
// 8 waves (2M x 4N), 128x128 tile, BK=64. Counted-vmcnt pipeline (T4).
__global__ __launch_bounds__(512) void gemm_qkv(
    const unsigned short* __restrict__ X, const unsigned short* __restrict__ Wt,
    const float* __restrict__ biasp,
    unsigned short* __restrict__ qs, unsigned short* __restrict__ ksd,
    unsigned short* __restrict__ vt) {
    __shared__ __align__(16) unsigned short shm[4 * 8192]; // 64 KB: A dbuf | B dbuf; reused as epilogue scratch

    const int bn = blockIdx.x, bm = blockIdx.y;
    const int m0 = bm * 128, n0 = bn * 128;
    const int t = threadIdx.x, wave = t >> 6, lane = t & 63, g = lane >> 4, li = lane & 15;
    const int wr = wave >> 2, wc = wave & 3;

    const int rowb = t >> 3;
    const int soff = ((t & 7) ^ (rowb & 7)) * 8; // row+64 has same row&7
    const unsigned short* Xrow = X + (size_t)(m0 + rowb) * 1024 + soff;
    const unsigned short* Wrow = Wt + (size_t)(n0 + rowb) * 1024 + soff;

    f32x4 acc[4][2];
#pragma unroll
    for (int i = 0; i < 4; ++i)
#pragma unroll
        for (int j = 0; j < 2; ++j) acc[i][j] = (f32x4){0.f, 0.f, 0.f, 0.f};

    // prologue: stage kt=0 into buffer 0 (4 loads/thread)
#pragma unroll
    for (int i = 0; i < 2; ++i) {
        gload16(Xrow + (size_t)i * 64 * 1024, &shm[(i * 512 + t) * 8]);
        gload16(Wrow + (size_t)i * 64 * 1024, &shm[16384 + (i * 512 + t) * 8]);
    }

    for (int kt = 0; kt < 16; ++kt) {
        const int cur = kt & 1;
        __builtin_amdgcn_s_barrier(); // all waves done reading buf[cur^1] (prev compute)
        if (kt < 15) {
            const int k0n = (kt + 1) * 64;
            unsigned short* An = &shm[(cur ^ 1) * 8192];
            unsigned short* Bn = &shm[16384 + (cur ^ 1) * 8192];
#pragma unroll
            for (int i = 0; i < 2; ++i) {
                gload16(Xrow + (size_t)i * 64 * 1024 + k0n, &An[(i * 512 + t) * 8]);
                gload16(Wrow + (size_t)i * 64 * 1024 + k0n, &Bn[(i * 512 + t) * 8]);
            }
            asm volatile("s_waitcnt vmcnt(4)" ::: "memory"); // cur's 4 landed; next's in flight
        } else {
            asm volatile("s_waitcnt vmcnt(0)" ::: "memory");
        }
        __builtin_amdgcn_s_barrier(); // every wave's cur-loads landed
        const unsigned short* Al = &shm[cur * 8192];
        const unsigned short* Bl = &shm[16384 + cur * 8192];
        __builtin_amdgcn_s_setprio(1);
#pragma unroll
        for (int ks = 0; ks < 2; ++ks) {
            bf16x8 af[4], bf[2];
#pragma unroll
            for (int mi = 0; mi < 4; ++mi) {
                int row = wr * 64 + mi * 16 + li;
                af[mi] = *(const bf16x8*)&Al[row * 64 + ((ks * 4 + g) ^ (row & 7)) * 8];
            }
#pragma unroll
            for (int ni = 0; ni < 2; ++ni) {
                int row = wc * 32 + ni * 16 + li;
                bf[ni] = *(const bf16x8*)&Bl[row * 64 + ((ks * 4 + g) ^ (row & 7)) * 8];
            }
#pragma unroll
            for (int mi = 0; mi < 4; ++mi)
#pragma unroll
                for (int ni = 0; ni < 2; ++ni)
                    acc[mi][ni] = __builtin_amdgcn_mfma_f32_16x16x32_bf16(af[mi], bf[ni],
                                                                          acc[mi][ni], 0, 0, 0);
        }
        __builtin_amdgcn_s_setprio(0);
    }
    __syncthreads(); // all compute done before scratch reuse of shm

    float bvals[2];
#pragma unroll
    for (int ni = 0; ni < 2; ++ni) bvals[ni] = biasp[n0 + wc * 32 + ni * 16 + li];

    const int region = n0 >> 10; // block-uniform: 0=q, 1=k, 2=v
    float* scr = (float*)shm;

    if (region < 2) {
        // q/k: per-wave scratch 16 rows x 36 stride
        float* wf = scr + wave * (16 * 36);
        unsigned short* dstbase = region == 0 ? qs : ksd;
        const int ncol0 = n0 + wc * 32;
        const int hh = (ncol0 & 1023) >> 6;
        const int dcol = (ncol0 & 63) + (lane & 3) * 8;
        const int lr = lane >> 2;
#pragma unroll
        for (int mi = 0; mi < 4; ++mi) {
#pragma unroll
            for (int r = 0; r < 4; ++r) {
                int rowl = g * 4 + r;
#pragma unroll
                for (int ni = 0; ni < 2; ++ni)
                    wf[rowl * 36 + ni * 16 + li] = acc[mi][ni][r] + bvals[ni];
            }
            int m = m0 + wr * 64 + mi * 16 + lr;
            int bb = m >> 11, l = m & 2047;
            unsigned short* dp = dstbase + ((size_t)(bb * 16 + hh) * 2048 + l) * 64 + dcol;
            float4 a0 = *(const float4*)&wf[lr * 36 + (lane & 3) * 8];
            float4 a1 = *(const float4*)&wf[lr * 36 + (lane & 3) * 8 + 4];
            unsigned short o8[8] = {f2bf(a0.x), f2bf(a0.y), f2bf(a0.z), f2bf(a0.w),
                                    f2bf(a1.x), f2bf(a1.y), f2bf(a1.z), f2bf(a1.w)};
            *(uint4*)dp = *(const uint4*)o8;
        }
    } else {
        // v: per-wave scratch 32 rows x 36 stride
        float* wf = scr + wave * (32 * 36);
        const int d32 = lane & 31, half = lane >> 5;
        const int dglob = ((n0 + wc * 32) & 63) + d32;
        const int hh = ((n0 + wc * 32) & 1023) >> 6;
#pragma unroll
        for (int ch2 = 0; ch2 < 2; ++ch2) {
#pragma unroll
            for (int mi2 = 0; mi2 < 2; ++mi2) {
                int mi = ch2 * 2 + mi2;
#pragma unroll
                for (int r = 0; r < 4; ++r) {
                    int rowl = mi2 * 16 + g * 4 + r;
#pragma unroll
                    for (int ni = 0; ni < 2; ++ni)
                        wf[rowl * 36 + ni * 16 + li] = acc[mi][ni][r] + bvals[ni];
                }
            }
            int l0 = m0 + wr * 64 + ch2 * 32;
            int bb = l0 >> 11, lb = (l0 & 2047) + half * 16;
            unsigned short* dp = vt + ((size_t)(bb * 16 + hh) * 64 + dglob) * 2048 + lb;
#pragma unroll
            for (int q8 = 0; q8 < 2; ++q8) {
                unsigned short o8[8];
#pragma unroll
                for (int j = 0; j < 8; ++j)
                    o8[j] = f2bf(wf[(half * 16 + q8 * 8 + j) * 36 + d32]);
                *(uint4*)(dp + q8 * 8) = *(const uint4*)o8;
            }
        }
    }
}

// ---------------------------------------------------------------- flash attention
// grid (16 qtiles, 32 bh), 512 threads = 8 waves x 16 q-rows. KVBLK=128, double-
// buffered, DMA-staged. Counted-vmcnt pipeline (T4): two raw barriers per period,
// s_waitcnt vmcnt(4) instead of full drain. No online max (scores O(1)):
// P = exp2(S+bias); denominator via all-ones B-fragment MFMA. No cross-lane ops.
__global__ __launch_bounds__(512) void attn_kernel(
    const unsigned short* __restrict__ qs, const unsigned short* __restrict__ ksrc,
    const unsigned short* __restrict__ vt, const float* __restrict__ fbias,
    float* __restrict__ out) {
    const int qt = blockIdx.x, bh = blockIdx.y;
    const int h = bh & 15, b = bh >> 4;
    const int t = threadIdx.x, wave = t >> 6, lane = t & 63, g = lane >> 4, li = lane & 15;

    __shared__ unsigned short Klds[2][2][64 * 64];
    __shared__ unsigned short Vlds[2][2][64 * 64];
    __shared__ unsigned short Plds[8][16 * 64];

    const float* fbh = fbias + (size_t)h * 2048;
    const unsigned short* Kg = ksrc + (size_t)bh * L_SEQ * 64;
    const unsigned short* Vg = vt + (size_t)bh * 64 * L_SEQ;

    const int im = qt * 128 + wave * 16;
    const unsigned short* qb = qs + ((size_t)bh * L_SEQ + im + li) * 64;
    bf16x8 qa0 = *(const bf16x8*)(qb + g * 8);
    bf16x8 qa1 = *(const bf16x8*)(qb + 32 + g * 8);

    bf16x8 onesv;
#pragma unroll
    for (int i = 0; i < 8; ++i) onesv[i] = (short)0x3F80; // bf16(1.0)

    f32x4 o[5]; // [0..3]: output d-blocks; [4]: row-sum of P (softmax denominator)
#pragma unroll
    for (int i = 0; i < 5; ++i) o[i] = (f32x4){0.f, 0.f, 0.f, 0.f};

    const int iout0 = im + g * 4;

    // wave-level band union: q-rows [im, im+15]
    int lo_min = im - 32; lo_min = lo_min < 0 ? 0 : (lo_min > 1984 ? 1984 : lo_min);
    int hi_tmp = im + 15 - 32; hi_tmp = hi_tmp < 0 ? 0 : (hi_tmp > 1984 ? 1984 : hi_tmp);
    const int hi_max = hi_tmp + 63;

    // per-thread DMA chunk geometry (16B per tensor per sub-tile per thread)
    const int r0 = t >> 3, s0 = ((t & 7) ^ (r0 & 7)) * 8;

    // prologue: stage tile-pair 0 into buffer 0 (4 loads/thread)
#pragma unroll
    for (int sub = 0; sub < 2; ++sub) {
        gload16(Kg + (size_t)(sub * 64 + r0) * 64 + s0, &Klds[0][sub][t * 8]);
        gload16(Vg + (size_t)r0 * L_SEQ + sub * 64 + s0, &Vlds[0][sub][t * 8]);
    }

    for (int jp = 0; jp < 16; ++jp) {
        const int cur = jp & 1;

        __builtin_amdgcn_s_barrier(); // all waves done reading buf[cur^1] (prev compute)
        if (jp < 15) {
            const int jb = (jp + 1) * 128;
#pragma unroll
            for (int sub = 0; sub < 2; ++sub) {
                gload16(Kg + (size_t)(jb + sub * 64 + r0) * 64 + s0, &Klds[cur ^ 1][sub][t * 8]);
                gload16(Vg + (size_t)r0 * L_SEQ + jb + sub * 64 + s0, &Vlds[cur ^ 1][sub][t * 8]);
            }
            asm volatile("s_waitcnt vmcnt(4)" ::: "memory"); // cur's 4 landed; next's in flight
        } else {
            asm volatile("s_waitcnt vmcnt(0)" ::: "memory");
        }
        __builtin_amdgcn_s_barrier(); // every wave's cur-loads landed

#pragma unroll
        for (int sub = 0; sub < 2; ++sub) {
            const int j0 = jp * 128 + sub * 64;
            const unsigned short* Kl = Klds[cur][sub];
            const unsigned short* Vl = Vlds[cur][sub];

            // S = q~ K^T  (rows: 16 q-rows of this wave, cols: 64 j)
            f32x4 s[4];
#pragma unroll
            for (int nb = 0; nb < 4; ++nb) s[nb] = (f32x4){0.f, 0.f, 0.f, 0.f};
            __builtin_amdgcn_s_setprio(1);
#pragma unroll
            for (int ks = 0; ks < 2; ++ks) {
                bf16x8 qf = ks ? qa1 : qa0;
#pragma unroll
                for (int nb = 0; nb < 4; ++nb) {
                    int row = nb * 16 + li;
                    bf16x8 kf = *(const bf16x8*)&Kl[row * 64 + ((ks * 4 + g) ^ (row & 7)) * 8];
                    s[nb] = __builtin_amdgcn_mfma_f32_16x16x32_bf16(qf, kf, s[nb], 0, 0, 0);
                }
            }
            __builtin_amdgcn_s_setprio(0);

            // P = exp2(S [+ banded bias]) -> per-wave swizzled LDS (row=g*4+r, col=nb*16+li)
            const bool bias_tile = (j0 + 63 >= lo_min) && (j0 <= hi_max);
            unsigned short* Pw = Plds[wave];
#pragma unroll
            for (int r = 0; r < 4; ++r) {
                int iout = iout0 + r;
                int row = g * 4 + r;
                if (bias_tile) {
                    int lo = iout - 32;
                    lo = lo < 0 ? 0 : (lo > 1984 ? 1984 : lo);
#pragma unroll
                    for (int nb = 0; nb < 4; ++nb) {
                        int j = j0 + nb * 16 + li;
                        float x = s[nb][r];
                        int dd = iout - j; dd = dd < 0 ? -dd : dd;
                        if ((unsigned)(j - lo) < 64u) x += fbh[dd];
                        int col = nb * 16 + li;
                        Pw[row * 64 + (col ^ ((row & 7) << 3))] = f2bf(exp2_fast(x));
                    }
                } else {
#pragma unroll
                    for (int nb = 0; nb < 4; ++nb) {
                        int col = nb * 16 + li;
                        Pw[row * 64 + (col ^ ((row & 7) << 3))] = f2bf(exp2_fast(s[nb][r]));
                    }
                }
            }

            bf16x8 pa0 = *(const bf16x8*)&Pw[li * 64 + ((0 + g) ^ (li & 7)) * 8];
            bf16x8 pa1 = *(const bf16x8*)&Pw[li * 64 + ((4 + g) ^ (li & 7)) * 8];
            __builtin_amdgcn_s_setprio(1);
#pragma unroll
            for (int db = 0; db < 4; ++db) {
                int row = db * 16 + li;
                bf16x8 v0 = *(const bf16x8*)&Vl[row * 64 + ((0 + g) ^ (row & 7)) * 8];
                bf16x8 v1 = *(const bf16x8*)&Vl[row * 64 + ((4 + g) ^ (row & 7)) * 8];
                o[db] = __builtin_amdgcn_mfma_f32_16x16x32_bf16(pa0, v0, o[db], 0, 0, 0);
                o[db] = __builtin_amdgcn_mfma_f32_16x16x32_bf16(pa1, v1, o[db], 0, 0, 0);
            }
            // denominator: C[r][*] += sum_k P[r][k] * 1  (same value in every lane)
            o[4] = __builtin_amdgcn_mfma_f32_16x16x32_bf16(pa0, onesv, o[4], 0, 0, 0);
            o[4] = __builtin_amdgcn_mfma_f32_16x16x32_bf16(pa1, onesv, o[4], 0, 0, 0);
            __builtin_amdgcn_s_setprio(0);
        }
    }

    float* ob = out + (size_t)b * L_SEQ * 1024 + h * 64;
#pragma unroll
    for (int r = 0; r < 4; ++r) {
        float rl = 1.f / o[4][r];
        int iout = iout0 + r;
#pragma unroll
        for (int db = 0; db < 4; ++db)
            ob[(size_t)iout * 1024 + db * 16 + li] = o[db][r] * rl;
    }
}

// ----------------------------------------------------------------
extern "C" void kernel_launch(void* const* d_in, const int* in_sizes, int n_in,
                              void* d_out, int out_size, void* d_ws, size_t ws_size,
                              hipStream_t stream) {
    const float* hs = (const float*)d_in[0];
    const float* Wq = (const float*)d_in[1];
    const float* bq = (const float*)d_in[2];
    const float* Wk = (const float*)d_in[3];
    const float* bk = (const float*)d_in[4];
    const float* Wv = (const float*)d_in[5];
    const float* bv = (const float*)d_in[6];
    const float* coef = (const float*)d_in[7];
    const float* Pq = (const float*)d_in[8];
    const float* Pk = (const float*)d_in[9];
    float* out = (float*)d_out;

    char* w = (char*)d_ws;
    float* M = (float*)(w);                              // 256 KB
    float* fbias = (float*)(w + 0x40000);                // 128 KB
    float* biasp = (float*)(w + 0x60000);                // 12 KB
    unsigned short* Wt = (unsigned short*)(w + 0x70000); // 6 MB
    unsigned short* X = (unsigned short*)(w + 0x670000); // 8 MB
    unsigned short* qs = (unsigned short*)(w + 0xE70000);
    unsigned short* ks = (unsigned short*)(w + 0x1670000);
    unsigned short* vt = (unsigned short*)(w + 0x2670000);

    hipLaunchKernelGGL(compute_M, dim3(16, 16), dim3(256), 0, stream, Pq, Pk, M);
    hipLaunchKernelGGL(bias_table_kernel, dim3(128), dim3(256), 0, stream, coef, fbias);
    hipLaunchKernelGGL(build_wtq, dim3(16, 16), dim3(256), 0, stream, Wq, bq, M, Wt, biasp);
    hipLaunchKernelGGL(transpose_wkv, dim3(16, 16, 2), dim3(256), 0, stream,
                       Wk, Wv, bk, bv, Wt, biasp);
    hipLaunchKernelGGL(cast_hs_kernel, dim3(4096), dim3(256), 0, stream, hs, X);
    hipLaunchKernelGGL(gemm_qkv, dim3(24, 32), dim3(512), 0, stream, X, Wt, biasp, qs, ks, vt);
    hipLaunchKernelGGL(attn_kernel, dim3(16, 32), dim3(512), 0, stream, qs, ks, vt, fbias, out);
}